// Round 9
// baseline (318.121 us; speedup 1.0000x reference)
//
#include <hip/hip_runtime.h>
#include <hip/hip_bf16.h>
#include <stdint.h>

typedef unsigned short u16;
typedef __attribute__((ext_vector_type(4))) unsigned short u16x4;
typedef __attribute__((ext_vector_type(8))) short short8;
typedef __attribute__((ext_vector_type(4))) float f32x4;

__device__ inline u16 f2b(float f) {
  uint32_t u = __builtin_bit_cast(uint32_t, f);
  u += 0x7fffu + ((u >> 16) & 1u);   // RNE round to bf16
  return (u16)(u >> 16);
}

// ---------------- fused prep: x->bf16, W transpose+cvt, bias concat, rowsum zero --------
__global__ __launch_bounds__(256) void prep(
    const float* __restrict__ x, u16* __restrict__ xb,
    const float* __restrict__ Wq, const float* __restrict__ Wk,
    const float* __restrict__ Wv, u16* __restrict__ wT,
    const float* __restrict__ bq, const float* __restrict__ bk,
    const float* __restrict__ bv, float* __restrict__ biasC,
    float* __restrict__ rowsum) {
  __shared__ float tl[32][33];
  const int b = blockIdx.x;
  const int t = threadIdx.x;
  if (b < 8192) {
    long i = ((long)b * 256 + t) * 4;
    float4 v = *(const float4*)(x + i);
    u16x4 o = { f2b(v.x), f2b(v.y), f2b(v.z), f2b(v.w) };
    *(u16x4*)(xb + i) = o;
  } else if (b < 8192 + 3072) {
    const int bb = b - 8192;
    const int z = bb >> 10;            // 0..2 -> Wq/Wk/Wv
    const int tile = bb & 1023;
    const float* in = z == 0 ? Wq : (z == 1 ? Wk : Wv);
    u16* o = wT + (long)z * 1024 * 1024;
    const int c0 = (tile & 31) * 32, r0 = (tile >> 5) * 32;
    const int tx = t & 31, ty = t >> 5;   // 32 x 8
#pragma unroll
    for (int j = 0; j < 32; j += 8)
      tl[ty + j][tx] = in[(long)(r0 + ty + j) * 1024 + c0 + tx];
    __syncthreads();
#pragma unroll
    for (int j = 0; j < 32; j += 8)
      o[(long)(c0 + ty + j) * 1024 + r0 + tx] = f2b(tl[tx][ty + j]);
  } else {
    const int i = (b - 8192 - 3072) * 256 + t;
    if (i < 3072)
      biasC[i] = i < 1024 ? bq[i] : (i < 2048 ? bk[i - 1024] : bv[i - 2048]);
    else if (i < 3072 + 8192)
      rowsum[i - 3072] = 0.0f;
  }
}

#define BM 128
#define BN 128
#define BK 64

__device__ inline void load_lds16(const void* g, void* l) {
  __builtin_amdgcn_global_load_lds((const __attribute__((address_space(1))) void*)g,
                                   (__attribute__((address_space(3))) void*)l, 16, 0, 0);
}

// ---------------- 128x128 bt-GEMM, XOR-swizzled LDS, XCD-chunked block swizzle ----------
// 1D grid; logical tile s = (b&7)*swq + (b>>3)  (bijective: grid%8==0).
// Each XCD receives a CONTIGUOUS run of logical tiles -> operand panels shared by
// neighboring tiles stay in that XCD's L2 (R7: scores FETCH 114->67.6 MB = mask-only).
// MODE 0: QKV epilogue (bias; cols>=2048 pre-transposed into vtOut)
// MODE 2: scores epilogue: P = exp(v*scale + mask) bf16; rowsum[row] += partials.
//         Mask tile (128x128 fp32 = 64 KB) staged through LDS with coalesced
//         float4 loads, then read per-lane (q4-rotated j-order -> 2-way = free).
// MODE 4: PV epilogue: fp32, v / rowsum[row]
template <int MODE>
__global__ __launch_bounds__(256, 2) void gemm_bt(
    const u16* __restrict__ A, const u16* __restrict__ Bt, void* __restrict__ C,
    u16* __restrict__ vtOut, const float* __restrict__ bias,
    float* __restrict__ rsum, const float* __restrict__ maskG,
    int K, int lda, int ldb, int ldc,
    long sA_, long sB_, long sC_, float scale,
    int swq, int tpz, int nx)
{
  // XCD-chunked bijective swizzle, then decode (z, by, bx)
  const int b = blockIdx.x;
  const int s = (b & 7) * swq + (b >> 3);
  const int z = s / tpz, rem = s % tpz;
  const int bx = rem % nx, by = rem / nx;

  A += z * sA_;
  Bt += z * sB_;
  const long cbase = z * sC_;

  // MODE 2 gets 64 KB (mask tile staging in epilogue); others 32 KB.
  // 2 blocks/CU: 128 KB <= 160 KB -> occupancy unchanged.
  __shared__ __align__(16) u16 ldsbuf[(MODE == 2 ? 4 : 2) * BM * BK];
  u16* lA = ldsbuf;
  u16* lB = ldsbuf + BM * BK;

  const int t = threadIdx.x;
  const int lane = t & 63;
  const int wave = t >> 6;
  const int wr = wave >> 1, wc = wave & 1;
  const int m0 = by * BM, n0 = bx * BN;

  // Staging: LDS [128 rows][8 chunks of 8 u16]; slot s of row r holds global
  // chunk s ^ (r&7) -> conflict-free ds_read_b128; linear LDS dest (rule 21).
  const int srow = t >> 3;
  const int schunk = (t & 7) ^ (srow & 7);
  const u16* aS = A + (long)(m0 + srow) * lda + schunk * 8;
  const u16* bS = Bt + (long)(n0 + srow) * ldb + schunk * 8;

  f32x4 acc[4][4] = {};
  const int fr = lane & 15;
  const int q4 = lane >> 4;

  for (int k0 = 0; k0 < K; k0 += BK) {
    __syncthreads();                 // prior LDS reads done before overwrite
#pragma unroll
    for (int i = 0; i < 4; i++) {
      load_lds16(aS + k0 + (long)(i * 32) * lda, &lA[(i * 256 + t) * 8]);
      load_lds16(bS + k0 + (long)(i * 32) * ldb, &lB[(i * 256 + t) * 8]);
    }
    __syncthreads();                 // drain global_load_lds
#pragma unroll
    for (int kk = 0; kk < 2; kk++) {
      const int ch = kk * 4 + q4;
      short8 aF[4], bF[4];
#pragma unroll
      for (int i = 0; i < 4; i++) {
        int row = wr * 64 + i * 16 + fr;
        aF[i] = *(const short8*)&lA[row * BK + ((ch ^ (row & 7)) * 8)];
      }
#pragma unroll
      for (int j = 0; j < 4; j++) {
        int row = wc * 64 + j * 16 + fr;
        bF[j] = *(const short8*)&lB[row * BK + ((ch ^ (row & 7)) * 8)];
      }
#pragma unroll
      for (int i = 0; i < 4; i++)
#pragma unroll
        for (int j = 0; j < 4; j++)
          acc[i][j] = __builtin_amdgcn_mfma_f32_16x16x32_bf16(aF[i], bF[j], acc[i][j], 0, 0, 0);
    }
  }

  // epilogue: C/D layout col = lane&15, row = (lane>>4)*4 + r
  const int r0 = q4 * 4;
  if (MODE == 2) {
    // ---- stage 128x128 fp32 mask tile into LDS, fully coalesced ----
    float* lm = (float*)ldsbuf;                    // 64 KB = 128*128 fp32
    const float* mk = maskG + (long)z * 2048 * 2048 + (long)m0 * 2048 + n0;
    __syncthreads();                               // all waves done with lA/lB
#pragma unroll
    for (int p = 0; p < 16; p++) {
      const int f = p * 256 + t;                   // float4 id: 128 rows x 32
      const int row = f >> 5, c4 = (f & 31) * 4;
      *(float4*)&lm[row * 128 + c4] = *(const float4*)&mk[(long)row * 2048 + c4];
    }
    __syncthreads();

    u16* Pout = (u16*)C + cbase;
    float* rz = rsum + (long)z * 2048;
#pragma unroll
    for (int i = 0; i < 4; i++) {
      const int lrow = wr * 64 + i * 16 + r0;      // local row (r adds 0..3)
      const int row = m0 + lrow;
      float ml[4][4];
#pragma unroll
      for (int jo = 0; jo < 4; jo++) {
        const int j = (jo + q4) & 3;               // rotate: 2-way banks (free)
        const int lcol = wc * 64 + j * 16 + fr;
#pragma unroll
        for (int r = 0; r < 4; r++)
          ml[j][r] = lm[(lrow + r) * 128 + lcol];
      }
      float rs[4] = {0.f, 0.f, 0.f, 0.f};
#pragma unroll
      for (int j = 0; j < 4; j++) {
        const int col = n0 + wc * 64 + j * 16 + fr;
#pragma unroll
        for (int r = 0; r < 4; r++) {
          float e = __expf(acc[i][j][r] * scale + ml[j][r]);
          Pout[(long)(row + r) * ldc + col] = f2b(e);
          rs[r] += e;
        }
      }
#pragma unroll
      for (int r = 0; r < 4; r++) {
        float s2 = rs[r];
        s2 += __shfl_xor(s2, 1); s2 += __shfl_xor(s2, 2);
        s2 += __shfl_xor(s2, 4); s2 += __shfl_xor(s2, 8);
        if (fr == 0) atomicAdd(&rz[row + r], s2);
      }
    }
  } else if (MODE == 0) {
#pragma unroll
    for (int i = 0; i < 4; i++) {
#pragma unroll
      for (int j = 0; j < 4; j++) {
        const int row = m0 + wr * 64 + i * 16 + r0;
        const int col = n0 + wc * 64 + j * 16 + fr;
        const float b2 = bias[col];
        if (col >= 2048) {
          u16x4 o = { f2b(acc[i][j][0] + b2), f2b(acc[i][j][1] + b2),
                      f2b(acc[i][j][2] + b2), f2b(acc[i][j][3] + b2) };
          *(u16x4*)(vtOut + (long)(col - 2048) * 8192 + row) = o;
        } else {
#pragma unroll
          for (int r = 0; r < 4; r++)
            ((u16*)C)[(long)(row + r) * ldc + col] = f2b(acc[i][j][r] + b2);
        }
      }
    }
  } else {
    const float* lz = rsum + (long)z * 2048;
#pragma unroll
    for (int i = 0; i < 4; i++) {
      const int row = m0 + wr * 64 + i * 16 + r0;
      float inv[4];
#pragma unroll
      for (int r = 0; r < 4; r++) inv[r] = 1.0f / lz[row + r];
#pragma unroll
      for (int j = 0; j < 4; j++) {
        const int col = n0 + wc * 64 + j * 16 + fr;
#pragma unroll
        for (int r = 0; r < 4; r++)
          ((float*)C)[cbase + (long)(row + r) * ldc + col] = acc[i][j][r] * inv[r];
      }
    }
  }
}

// ---------------- launch ----------------
extern "C" void kernel_launch(void* const* d_in, const int* in_sizes, int n_in,
                              void* d_out, int out_size, void* d_ws, size_t ws_size,
                              hipStream_t stream) {
  const float* x    = (const float*)d_in[0];   // [4,2048,1024]
  const float* mask = (const float*)d_in[1];   // [4,2048,2048]
  const float* Wq   = (const float*)d_in[2];
  const float* bq   = (const float*)d_in[3];
  const float* Wk   = (const float*)d_in[4];
  const float* bk   = (const float*)d_in[5];
  const float* Wv   = (const float*)d_in[6];
  const float* bv   = (const float*)d_in[7];
  float* out = (float*)d_out;

  char* w = (char*)d_ws;
  u16*   xb    = (u16*)(w);                 // x bf16      [8192,1024]
  u16*   wT    = (u16*)(w + 16777216);      // [Wq;Wk;Wv]^T bf16 [3072,1024]
  float* biasC = (float*)(w + 23068672);    // concat bias [3072]
  u16*   QKV   = (u16*)(w + 23081088);      // Q,K bf16    [8192,3072]
  u16*   Vt    = (u16*)(w + 73414016);      // V^T bf16    [1024,8192]
  u16*   Pp    = (u16*)(w + 90191232);      // P bf16      [4,2048,2048]
  float* rowsum= (float*)(w + 123745664);   // row sums    [8192]

  prep<<<8192 + 3072 + 44, 256, 0, stream>>>(x, xb, Wq, Wk, Wv, wT, bq, bk, bv, biasC, rowsum);

  // QKV: [8192,1024] x [3072,1024]^T -> Q,K + V^T.  1536 tiles, 24 per row.
  gemm_bt<0><<<1536, 256, 0, stream>>>(xb, wT, QKV, Vt, biasC, nullptr, nullptr,
      1024, 1024, 1024, 3072, 0, 0, 0, 1.0f,
      192, 1536, 24);

  // scores: P = exp(QK^T/32 + mask), rowsum in-epilogue.  1024 tiles = 4z x 16 x 16.
  gemm_bt<2><<<1024, 256, 0, stream>>>(QKV, QKV + 1024, Pp, nullptr, nullptr, rowsum, mask,
      1024, 3072, 3072, 2048,
      2048L * 3072, 2048L * 3072, 2048L * 2048, 0.03125f,
      128, 256, 16);

  // PV: out = (P V) / rowsum.  512 tiles = 4z x 16 x 8.
  gemm_bt<4><<<512, 256, 0, stream>>>(Pp, Vt, out, nullptr, nullptr, rowsum, nullptr,
      2048, 2048, 8192, 1024,
      2048L * 2048, 2048L, 2048L * 1024, 1.0f,
      64, 128, 8);
}

// Round 10
// 303.266 us; speedup vs baseline: 1.0490x; 1.0490x over previous
//
#include <hip/hip_runtime.h>
#include <hip/hip_bf16.h>
#include <stdint.h>

typedef unsigned short u16;
typedef __attribute__((ext_vector_type(4))) unsigned short u16x4;
typedef __attribute__((ext_vector_type(8))) short short8;
typedef __attribute__((ext_vector_type(4))) float f32x4;

__device__ inline u16 f2b(float f) {
  uint32_t u = __builtin_bit_cast(uint32_t, f);
  u += 0x7fffu + ((u >> 16) & 1u);   // RNE round to bf16
  return (u16)(u >> 16);
}

// ---------------- fused prep: x->bf16, W transpose+cvt, bias concat, rowsum zero --------
__global__ __launch_bounds__(256) void prep(
    const float* __restrict__ x, u16* __restrict__ xb,
    const float* __restrict__ Wq, const float* __restrict__ Wk,
    const float* __restrict__ Wv, u16* __restrict__ wT,
    const float* __restrict__ bq, const float* __restrict__ bk,
    const float* __restrict__ bv, float* __restrict__ biasC,
    float* __restrict__ rowsum) {
  __shared__ float tl[32][33];
  const int b = blockIdx.x;
  const int t = threadIdx.x;
  if (b < 8192) {
    long i = ((long)b * 256 + t) * 4;
    float4 v = *(const float4*)(x + i);
    u16x4 o = { f2b(v.x), f2b(v.y), f2b(v.z), f2b(v.w) };
    *(u16x4*)(xb + i) = o;
  } else if (b < 8192 + 3072) {
    const int bb = b - 8192;
    const int z = bb >> 10;            // 0..2 -> Wq/Wk/Wv
    const int tile = bb & 1023;
    const float* in = z == 0 ? Wq : (z == 1 ? Wk : Wv);
    u16* o = wT + (long)z * 1024 * 1024;
    const int c0 = (tile & 31) * 32, r0 = (tile >> 5) * 32;
    const int tx = t & 31, ty = t >> 5;   // 32 x 8
#pragma unroll
    for (int j = 0; j < 32; j += 8)
      tl[ty + j][tx] = in[(long)(r0 + ty + j) * 1024 + c0 + tx];
    __syncthreads();
#pragma unroll
    for (int j = 0; j < 32; j += 8)
      o[(long)(c0 + ty + j) * 1024 + r0 + tx] = f2b(tl[tx][ty + j]);
  } else {
    const int i = (b - 8192 - 3072) * 256 + t;
    if (i < 3072)
      biasC[i] = i < 1024 ? bq[i] : (i < 2048 ? bk[i - 1024] : bv[i - 2048]);
    else if (i < 3072 + 8192)
      rowsum[i - 3072] = 0.0f;
  }
}

#define BM 128
#define BN 128
#define BK 64

__device__ inline void load_lds16(const void* g, void* l) {
  __builtin_amdgcn_global_load_lds((const __attribute__((address_space(1))) void*)g,
                                   (__attribute__((address_space(3))) void*)l, 16, 0, 0);
}

// ---------------- 128x128 bt-GEMM, XOR-swizzled LDS, XCD-chunked block swizzle ----------
// 1D grid; logical tile s = (b&7)*swq + (b>>3)  (bijective: grid%8==0).
// Each XCD receives a CONTIGUOUS run of logical tiles -> operand panels shared by
// neighboring tiles stay in that XCD's L2 (R7: scores FETCH 114->67.6 MB = mask-only).
// MODE 0: QKV epilogue (bias; cols>=2048 pre-transposed into vtOut)
// MODE 2: scores epilogue: P = exp(v*scale + mask) bf16; rowsum[row] += partials.
//         Mask tile staged in LDS (coalesced float4), stride-132 pad -> <=2-way
//         banks (free, m136); all epilogue indices STATIC (R9's runtime-indexed
//         local array went to scratch — rule #20 — costing 2.2x).
// MODE 4: PV epilogue: fp32, v / rowsum[row]
template <int MODE>
__global__ __launch_bounds__(256, 2) void gemm_bt(
    const u16* __restrict__ A, const u16* __restrict__ Bt, void* __restrict__ C,
    u16* __restrict__ vtOut, const float* __restrict__ bias,
    float* __restrict__ rsum, const float* __restrict__ maskG,
    int K, int lda, int ldb, int ldc,
    long sA_, long sB_, long sC_, float scale,
    int swq, int tpz, int nx)
{
  // XCD-chunked bijective swizzle, then decode (z, by, bx)
  const int b = blockIdx.x;
  const int s = (b & 7) * swq + (b >> 3);
  const int z = s / tpz, rem = s % tpz;
  const int bx = rem % nx, by = rem / nx;

  A += z * sA_;
  Bt += z * sB_;
  const long cbase = z * sC_;

  // MODE 2: 66 KB (mask tile [128][132] fp32 staged in epilogue); else 32 KB.
  // 2 blocks/CU: 132 KB <= 160 KB -> occupancy unchanged.
  constexpr int LDSU16 = (MODE == 2) ? (128 * 132 * 2) : (2 * BM * BK);
  __shared__ __align__(16) u16 ldsbuf[LDSU16];
  u16* lA = ldsbuf;
  u16* lB = ldsbuf + BM * BK;

  const int t = threadIdx.x;
  const int lane = t & 63;
  const int wave = t >> 6;
  const int wr = wave >> 1, wc = wave & 1;
  const int m0 = by * BM, n0 = bx * BN;

  // Staging: LDS [128 rows][8 chunks of 8 u16]; slot s of row r holds global
  // chunk s ^ (r&7) -> conflict-free ds_read_b128; linear LDS dest (rule 21).
  const int srow = t >> 3;
  const int schunk = (t & 7) ^ (srow & 7);
  const u16* aS = A + (long)(m0 + srow) * lda + schunk * 8;
  const u16* bS = Bt + (long)(n0 + srow) * ldb + schunk * 8;

  f32x4 acc[4][4] = {};
  const int fr = lane & 15;
  const int q4 = lane >> 4;

  for (int k0 = 0; k0 < K; k0 += BK) {
    __syncthreads();                 // prior LDS reads done before overwrite
#pragma unroll
    for (int i = 0; i < 4; i++) {
      load_lds16(aS + k0 + (long)(i * 32) * lda, &lA[(i * 256 + t) * 8]);
      load_lds16(bS + k0 + (long)(i * 32) * ldb, &lB[(i * 256 + t) * 8]);
    }
    __syncthreads();                 // drain global_load_lds
#pragma unroll
    for (int kk = 0; kk < 2; kk++) {
      const int ch = kk * 4 + q4;
      short8 aF[4], bF[4];
#pragma unroll
      for (int i = 0; i < 4; i++) {
        int row = wr * 64 + i * 16 + fr;
        aF[i] = *(const short8*)&lA[row * BK + ((ch ^ (row & 7)) * 8)];
      }
#pragma unroll
      for (int j = 0; j < 4; j++) {
        int row = wc * 64 + j * 16 + fr;
        bF[j] = *(const short8*)&lB[row * BK + ((ch ^ (row & 7)) * 8)];
      }
#pragma unroll
      for (int i = 0; i < 4; i++)
#pragma unroll
        for (int j = 0; j < 4; j++)
          acc[i][j] = __builtin_amdgcn_mfma_f32_16x16x32_bf16(aF[i], bF[j], acc[i][j], 0, 0, 0);
    }
  }

  // epilogue: C/D layout col = lane&15, row = (lane>>4)*4 + r
  const int r0 = q4 * 4;
  if (MODE == 2) {
    // ---- stage 128x128 fp32 mask tile into LDS [128][132], coalesced float4 ----
    float* lm = (float*)ldsbuf;
    const float* mk = maskG + (long)z * 2048 * 2048 + (long)m0 * 2048 + n0;
    __syncthreads();                               // all waves done with lA/lB
#pragma unroll
    for (int p = 0; p < 16; p++) {
      const int f = p * 256 + t;                   // float4 id: 128 rows x 32
      const int mrow = f >> 5, c4 = (f & 31) * 4;
      *(float4*)&lm[mrow * 132 + c4] = *(const float4*)&mk[(long)mrow * 2048 + c4];
    }
    __syncthreads();

    u16* Pout = (u16*)C + cbase;
    float* rz = rsum + (long)z * 2048;
#pragma unroll
    for (int i = 0; i < 4; i++) {
      const int lrow = wr * 64 + i * 16 + r0;      // local row (r adds 0..3)
      const int row = m0 + lrow;
      float rs[4] = {0.f, 0.f, 0.f, 0.f};
#pragma unroll
      for (int j = 0; j < 4; j++) {
        const int lcol = wc * 64 + j * 16 + fr;
        const int col = n0 + lcol;
#pragma unroll
        for (int r = 0; r < 4; r++) {
          float e = __expf(acc[i][j][r] * scale + lm[(lrow + r) * 132 + lcol]);
          Pout[(long)(row + r) * ldc + col] = f2b(e);
          rs[r] += e;
        }
      }
#pragma unroll
      for (int r = 0; r < 4; r++) {
        float s2 = rs[r];
        s2 += __shfl_xor(s2, 1); s2 += __shfl_xor(s2, 2);
        s2 += __shfl_xor(s2, 4); s2 += __shfl_xor(s2, 8);
        if (fr == 0) atomicAdd(&rz[row + r], s2);
      }
    }
  } else if (MODE == 0) {
#pragma unroll
    for (int i = 0; i < 4; i++) {
#pragma unroll
      for (int j = 0; j < 4; j++) {
        const int row = m0 + wr * 64 + i * 16 + r0;
        const int col = n0 + wc * 64 + j * 16 + fr;
        const float b2 = bias[col];
        if (col >= 2048) {
          u16x4 o = { f2b(acc[i][j][0] + b2), f2b(acc[i][j][1] + b2),
                      f2b(acc[i][j][2] + b2), f2b(acc[i][j][3] + b2) };
          *(u16x4*)(vtOut + (long)(col - 2048) * 8192 + row) = o;
        } else {
#pragma unroll
          for (int r = 0; r < 4; r++)
            ((u16*)C)[(long)(row + r) * ldc + col] = f2b(acc[i][j][r] + b2);
        }
      }
    }
  } else {
    const float* lz = rsum + (long)z * 2048;
#pragma unroll
    for (int i = 0; i < 4; i++) {
      const int row = m0 + wr * 64 + i * 16 + r0;
      float inv[4];
#pragma unroll
      for (int r = 0; r < 4; r++) inv[r] = 1.0f / lz[row + r];
#pragma unroll
      for (int j = 0; j < 4; j++) {
        const int col = n0 + wc * 64 + j * 16 + fr;
#pragma unroll
        for (int r = 0; r < 4; r++)
          ((float*)C)[cbase + (long)(row + r) * ldc + col] = acc[i][j][r] * inv[r];
      }
    }
  }
}

// ---------------- launch ----------------
extern "C" void kernel_launch(void* const* d_in, const int* in_sizes, int n_in,
                              void* d_out, int out_size, void* d_ws, size_t ws_size,
                              hipStream_t stream) {
  const float* x    = (const float*)d_in[0];   // [4,2048,1024]
  const float* mask = (const float*)d_in[1];   // [4,2048,2048]
  const float* Wq   = (const float*)d_in[2];
  const float* bq   = (const float*)d_in[3];
  const float* Wk   = (const float*)d_in[4];
  const float* bk   = (const float*)d_in[5];
  const float* Wv   = (const float*)d_in[6];
  const float* bv   = (const float*)d_in[7];
  float* out = (float*)d_out;

  char* w = (char*)d_ws;
  u16*   xb    = (u16*)(w);                 // x bf16      [8192,1024]
  u16*   wT    = (u16*)(w + 16777216);      // [Wq;Wk;Wv]^T bf16 [3072,1024]
  float* biasC = (float*)(w + 23068672);    // concat bias [3072]
  u16*   QKV   = (u16*)(w + 23081088);      // Q,K bf16    [8192,3072]
  u16*   Vt    = (u16*)(w + 73414016);      // V^T bf16    [1024,8192]
  u16*   Pp    = (u16*)(w + 90191232);      // P bf16      [4,2048,2048]
  float* rowsum= (float*)(w + 123745664);   // row sums    [8192]

  prep<<<8192 + 3072 + 44, 256, 0, stream>>>(x, xb, Wq, Wk, Wv, wT, bq, bk, bv, biasC, rowsum);

  // QKV: [8192,1024] x [3072,1024]^T -> Q,K + V^T.  1536 tiles, 24 per row.
  gemm_bt<0><<<1536, 256, 0, stream>>>(xb, wT, QKV, Vt, biasC, nullptr, nullptr,
      1024, 1024, 1024, 3072, 0, 0, 0, 1.0f,
      192, 1536, 24);

  // scores: P = exp(QK^T/32 + mask), rowsum in-epilogue.  1024 tiles = 4z x 16 x 16.
  gemm_bt<2><<<1024, 256, 0, stream>>>(QKV, QKV + 1024, Pp, nullptr, nullptr, rowsum, mask,
      1024, 3072, 3072, 2048,
      2048L * 3072, 2048L * 3072, 2048L * 2048, 0.03125f,
      128, 256, 16);

  // PV: out = (P V) / rowsum.  512 tiles = 4z x 16 x 8.
  gemm_bt<4><<<512, 256, 0, stream>>>(Pp, Vt, out, nullptr, nullptr, rowsum, nullptr,
      2048, 2048, 8192, 1024,
      2048L * 2048, 2048L, 2048L * 1024, 1.0f,
      64, 128, 8);
}

// Round 11
// 300.702 us; speedup vs baseline: 1.0579x; 1.0085x over previous
//
#include <hip/hip_runtime.h>
#include <hip/hip_bf16.h>
#include <stdint.h>

typedef unsigned short u16;
typedef __attribute__((ext_vector_type(4))) unsigned short u16x4;
typedef __attribute__((ext_vector_type(8))) short short8;
typedef __attribute__((ext_vector_type(4))) float f32x4;

__device__ inline u16 f2b(float f) {
  uint32_t u = __builtin_bit_cast(uint32_t, f);
  u += 0x7fffu + ((u >> 16) & 1u);   // RNE round to bf16
  return (u16)(u >> 16);
}

// ---------------- fused prep: x->bf16, W transpose+cvt, bias concat, rowsum zero --------
__global__ __launch_bounds__(256) void prep(
    const float* __restrict__ x, u16* __restrict__ xb,
    const float* __restrict__ Wq, const float* __restrict__ Wk,
    const float* __restrict__ Wv, u16* __restrict__ wT,
    const float* __restrict__ bq, const float* __restrict__ bk,
    const float* __restrict__ bv, float* __restrict__ biasC,
    float* __restrict__ rowsum) {
  __shared__ float tl[32][33];
  const int b = blockIdx.x;
  const int t = threadIdx.x;
  if (b < 8192) {
    long i = ((long)b * 256 + t) * 4;
    float4 v = *(const float4*)(x + i);
    u16x4 o = { f2b(v.x), f2b(v.y), f2b(v.z), f2b(v.w) };
    *(u16x4*)(xb + i) = o;
  } else if (b < 8192 + 3072) {
    const int bb = b - 8192;
    const int z = bb >> 10;            // 0..2 -> Wq/Wk/Wv
    const int tile = bb & 1023;
    const float* in = z == 0 ? Wq : (z == 1 ? Wk : Wv);
    u16* o = wT + (long)z * 1024 * 1024;
    const int c0 = (tile & 31) * 32, r0 = (tile >> 5) * 32;
    const int tx = t & 31, ty = t >> 5;   // 32 x 8
#pragma unroll
    for (int j = 0; j < 32; j += 8)
      tl[ty + j][tx] = in[(long)(r0 + ty + j) * 1024 + c0 + tx];
    __syncthreads();
#pragma unroll
    for (int j = 0; j < 32; j += 8)
      o[(long)(c0 + ty + j) * 1024 + r0 + tx] = f2b(tl[tx][ty + j]);
  } else {
    const int i = (b - 8192 - 3072) * 256 + t;
    if (i < 3072)
      biasC[i] = i < 1024 ? bq[i] : (i < 2048 ? bk[i - 1024] : bv[i - 2048]);
    else if (i < 3072 + 8192)
      rowsum[i - 3072] = 0.0f;
  }
}

#define BM 128
#define BN 128
#define BK 64

__device__ inline void load_lds16(const void* g, void* l) {
  __builtin_amdgcn_global_load_lds((const __attribute__((address_space(1))) void*)g,
                                   (__attribute__((address_space(3))) void*)l, 16, 0, 0);
}

// ---------------- 128x128 bt-GEMM, XOR-swizzled LDS, XCD-chunked block swizzle ----------
// 1D grid; logical tile s = (b&7)*swq + (b>>3)  (bijective: grid%8==0).
// Each XCD receives a CONTIGUOUS run of logical tiles -> operand panels shared by
// neighboring tiles stay in that XCD's L2 (R7: scores FETCH 114->67.6 MB = mask-only).
// MODE 0: QKV epilogue (bias; cols>=2048 pre-transposed into vtOut)
// MODE 2: scores epilogue: P = exp(v*scale + mask) bf16; rowsum[row] += partials.
//         ALL 64 mask loads hoisted to epilogue top (static indices -> registers;
//         64-deep memory-level parallelism = one HBM round-trip, not four).
//         NOTE: loads must be AFTER the K-loop (R2: pre-loop pin -> VGPR live
//         across loop -> occupancy collapse) and direct-global (R10: LDS staging
//         of once-read data = serial stage chain, regressed 64.6->73).
// MODE 4: PV epilogue: fp32, v / rowsum[row]
template <int MODE>
__global__ __launch_bounds__(256, 2) void gemm_bt(
    const u16* __restrict__ A, const u16* __restrict__ Bt, void* __restrict__ C,
    u16* __restrict__ vtOut, const float* __restrict__ bias,
    float* __restrict__ rsum, const float* __restrict__ maskG,
    int K, int lda, int ldb, int ldc,
    long sA_, long sB_, long sC_, float scale,
    int swq, int tpz, int nx)
{
  // XCD-chunked bijective swizzle, then decode (z, by, bx)
  const int b = blockIdx.x;
  const int s = (b & 7) * swq + (b >> 3);
  const int z = s / tpz, rem = s % tpz;
  const int bx = rem % nx, by = rem / nx;

  A += z * sA_;
  Bt += z * sB_;
  const long cbase = z * sC_;

  __shared__ __align__(16) u16 lA[BM * BK];   // 16 KB
  __shared__ __align__(16) u16 lB[BN * BK];   // 16 KB

  const int t = threadIdx.x;
  const int lane = t & 63;
  const int wave = t >> 6;
  const int wr = wave >> 1, wc = wave & 1;
  const int m0 = by * BM, n0 = bx * BN;

  // Staging: LDS [128 rows][8 chunks of 8 u16]; slot s of row r holds global
  // chunk s ^ (r&7) -> conflict-free ds_read_b128; linear LDS dest (rule 21).
  const int srow = t >> 3;
  const int schunk = (t & 7) ^ (srow & 7);
  const u16* aS = A + (long)(m0 + srow) * lda + schunk * 8;
  const u16* bS = Bt + (long)(n0 + srow) * ldb + schunk * 8;

  f32x4 acc[4][4] = {};
  const int fr = lane & 15;
  const int q4 = lane >> 4;

  for (int k0 = 0; k0 < K; k0 += BK) {
    __syncthreads();                 // prior LDS reads done before overwrite
#pragma unroll
    for (int i = 0; i < 4; i++) {
      load_lds16(aS + k0 + (long)(i * 32) * lda, &lA[(i * 256 + t) * 8]);
      load_lds16(bS + k0 + (long)(i * 32) * ldb, &lB[(i * 256 + t) * 8]);
    }
    __syncthreads();                 // drain global_load_lds
#pragma unroll
    for (int kk = 0; kk < 2; kk++) {
      const int ch = kk * 4 + q4;
      short8 aF[4], bF[4];
#pragma unroll
      for (int i = 0; i < 4; i++) {
        int row = wr * 64 + i * 16 + fr;
        aF[i] = *(const short8*)&lA[row * BK + ((ch ^ (row & 7)) * 8)];
      }
#pragma unroll
      for (int j = 0; j < 4; j++) {
        int row = wc * 64 + j * 16 + fr;
        bF[j] = *(const short8*)&lB[row * BK + ((ch ^ (row & 7)) * 8)];
      }
#pragma unroll
      for (int i = 0; i < 4; i++)
#pragma unroll
        for (int j = 0; j < 4; j++)
          acc[i][j] = __builtin_amdgcn_mfma_f32_16x16x32_bf16(aF[i], bF[j], acc[i][j], 0, 0, 0);
    }
  }

  // epilogue: C/D layout col = lane&15, row = (lane>>4)*4 + r
  const int r0 = q4 * 4;
  if (MODE == 2) {
    const float* mk = maskG + (long)z * 2048 * 2048;
    u16* Pout = (u16*)C + cbase;
    float* rz = rsum + (long)z * 2048;
    // ---- issue ALL 64 mask loads up front (static indices -> 64 registers) ----
    float ml[4][4][4];
#pragma unroll
    for (int i = 0; i < 4; i++) {
      const int row = m0 + wr * 64 + i * 16 + r0;
#pragma unroll
      for (int j = 0; j < 4; j++) {
        const int col = n0 + wc * 64 + j * 16 + fr;
#pragma unroll
        for (int r = 0; r < 4; r++)
          ml[i][j][r] = mk[(long)(row + r) * 2048 + col];
      }
    }
    // ---- exp + store + rowsum reduce ----
#pragma unroll
    for (int i = 0; i < 4; i++) {
      const int row = m0 + wr * 64 + i * 16 + r0;
      float rs[4] = {0.f, 0.f, 0.f, 0.f};
#pragma unroll
      for (int j = 0; j < 4; j++) {
        const int col = n0 + wc * 64 + j * 16 + fr;
#pragma unroll
        for (int r = 0; r < 4; r++) {
          float e = __expf(acc[i][j][r] * scale + ml[i][j][r]);
          Pout[(long)(row + r) * ldc + col] = f2b(e);
          rs[r] += e;
        }
      }
#pragma unroll
      for (int r = 0; r < 4; r++) {
        float s2 = rs[r];
        s2 += __shfl_xor(s2, 1); s2 += __shfl_xor(s2, 2);
        s2 += __shfl_xor(s2, 4); s2 += __shfl_xor(s2, 8);
        if (fr == 0) atomicAdd(&rz[row + r], s2);
      }
    }
  } else if (MODE == 0) {
#pragma unroll
    for (int i = 0; i < 4; i++) {
#pragma unroll
      for (int j = 0; j < 4; j++) {
        const int row = m0 + wr * 64 + i * 16 + r0;
        const int col = n0 + wc * 64 + j * 16 + fr;
        const float b2 = bias[col];
        if (col >= 2048) {
          u16x4 o = { f2b(acc[i][j][0] + b2), f2b(acc[i][j][1] + b2),
                      f2b(acc[i][j][2] + b2), f2b(acc[i][j][3] + b2) };
          *(u16x4*)(vtOut + (long)(col - 2048) * 8192 + row) = o;
        } else {
#pragma unroll
          for (int r = 0; r < 4; r++)
            ((u16*)C)[(long)(row + r) * ldc + col] = f2b(acc[i][j][r] + b2);
        }
      }
    }
  } else {
    const float* lz = rsum + (long)z * 2048;
#pragma unroll
    for (int i = 0; i < 4; i++) {
      const int row = m0 + wr * 64 + i * 16 + r0;
      float inv[4];
#pragma unroll
      for (int r = 0; r < 4; r++) inv[r] = 1.0f / lz[row + r];
#pragma unroll
      for (int j = 0; j < 4; j++) {
        const int col = n0 + wc * 64 + j * 16 + fr;
#pragma unroll
        for (int r = 0; r < 4; r++)
          ((float*)C)[cbase + (long)(row + r) * ldc + col] = acc[i][j][r] * inv[r];
      }
    }
  }
}

// ---------------- launch ----------------
extern "C" void kernel_launch(void* const* d_in, const int* in_sizes, int n_in,
                              void* d_out, int out_size, void* d_ws, size_t ws_size,
                              hipStream_t stream) {
  const float* x    = (const float*)d_in[0];   // [4,2048,1024]
  const float* mask = (const float*)d_in[1];   // [4,2048,2048]
  const float* Wq   = (const float*)d_in[2];
  const float* bq   = (const float*)d_in[3];
  const float* Wk   = (const float*)d_in[4];
  const float* bk   = (const float*)d_in[5];
  const float* Wv   = (const float*)d_in[6];
  const float* bv   = (const float*)d_in[7];
  float* out = (float*)d_out;

  char* w = (char*)d_ws;
  u16*   xb    = (u16*)(w);                 // x bf16      [8192,1024]
  u16*   wT    = (u16*)(w + 16777216);      // [Wq;Wk;Wv]^T bf16 [3072,1024]
  float* biasC = (float*)(w + 23068672);    // concat bias [3072]
  u16*   QKV   = (u16*)(w + 23081088);      // Q,K bf16    [8192,3072]
  u16*   Vt    = (u16*)(w + 73414016);      // V^T bf16    [1024,8192]
  u16*   Pp    = (u16*)(w + 90191232);      // P bf16      [4,2048,2048]
  float* rowsum= (float*)(w + 123745664);   // row sums    [8192]

  prep<<<8192 + 3072 + 44, 256, 0, stream>>>(x, xb, Wq, Wk, Wv, wT, bq, bk, bv, biasC, rowsum);

  // QKV: [8192,1024] x [3072,1024]^T -> Q,K + V^T.  1536 tiles, 24 per row.
  gemm_bt<0><<<1536, 256, 0, stream>>>(xb, wT, QKV, Vt, biasC, nullptr, nullptr,
      1024, 1024, 1024, 3072, 0, 0, 0, 1.0f,
      192, 1536, 24);

  // scores: P = exp(QK^T/32 + mask), rowsum in-epilogue.  1024 tiles = 4z x 16 x 16.
  gemm_bt<2><<<1024, 256, 0, stream>>>(QKV, QKV + 1024, Pp, nullptr, nullptr, rowsum, mask,
      1024, 3072, 3072, 2048,
      2048L * 3072, 2048L * 3072, 2048L * 2048, 0.03125f,
      128, 256, 16);

  // PV: out = (P V) / rowsum.  512 tiles = 4z x 16 x 8.
  gemm_bt<4><<<512, 256, 0, stream>>>(Pp, Vt, out, nullptr, nullptr, rowsum, nullptr,
      2048, 2048, 8192, 1024,
      2048L * 2048, 2048L, 2048L * 1024, 1.0f,
      64, 128, 8);
}

// Round 12
// 293.404 us; speedup vs baseline: 1.0842x; 1.0249x over previous
//
#include <hip/hip_runtime.h>
#include <hip/hip_bf16.h>
#include <stdint.h>

typedef unsigned short u16;
typedef __attribute__((ext_vector_type(4))) unsigned short u16x4;
typedef __attribute__((ext_vector_type(8))) short short8;
typedef __attribute__((ext_vector_type(4))) float f32x4;

__device__ inline u16 f2b(float f) {
  uint32_t u = __builtin_bit_cast(uint32_t, f);
  u += 0x7fffu + ((u >> 16) & 1u);   // RNE round to bf16
  return (u16)(u >> 16);
}

// ---------------- fused prep: x->bf16, W transpose+cvt, bias concat, rowsum zero --------
__global__ __launch_bounds__(256) void prep(
    const float* __restrict__ x, u16* __restrict__ xb,
    const float* __restrict__ Wq, const float* __restrict__ Wk,
    const float* __restrict__ Wv, u16* __restrict__ wT,
    const float* __restrict__ bq, const float* __restrict__ bk,
    const float* __restrict__ bv, float* __restrict__ biasC,
    float* __restrict__ rowsum) {
  __shared__ float tl[32][33];
  const int b = blockIdx.x;
  const int t = threadIdx.x;
  if (b < 8192) {
    long i = ((long)b * 256 + t) * 4;
    float4 v = *(const float4*)(x + i);
    u16x4 o = { f2b(v.x), f2b(v.y), f2b(v.z), f2b(v.w) };
    *(u16x4*)(xb + i) = o;
  } else if (b < 8192 + 3072) {
    const int bb = b - 8192;
    const int z = bb >> 10;            // 0..2 -> Wq/Wk/Wv
    const int tile = bb & 1023;
    const float* in = z == 0 ? Wq : (z == 1 ? Wk : Wv);
    u16* o = wT + (long)z * 1024 * 1024;
    const int c0 = (tile & 31) * 32, r0 = (tile >> 5) * 32;
    const int tx = t & 31, ty = t >> 5;   // 32 x 8
#pragma unroll
    for (int j = 0; j < 32; j += 8)
      tl[ty + j][tx] = in[(long)(r0 + ty + j) * 1024 + c0 + tx];
    __syncthreads();
#pragma unroll
    for (int j = 0; j < 32; j += 8)
      o[(long)(c0 + ty + j) * 1024 + r0 + tx] = f2b(tl[tx][ty + j]);
  } else {
    const int i = (b - 8192 - 3072) * 256 + t;
    if (i < 3072)
      biasC[i] = i < 1024 ? bq[i] : (i < 2048 ? bk[i - 1024] : bv[i - 2048]);
    else if (i < 3072 + 8192)
      rowsum[i - 3072] = 0.0f;
  }
}

#define BM 128
#define BN 128
#define BK 64

__device__ inline void load_lds16(const void* g, void* l) {
  __builtin_amdgcn_global_load_lds((const __attribute__((address_space(1))) void*)g,
                                   (__attribute__((address_space(3))) void*)l, 16, 0, 0);
}

// ---------------- 128x128 bt-GEMM, XOR-swizzled LDS, XCD-chunked block swizzle ----------
// 1D grid; logical tile s = (b&7)*swq + (b>>3)  (bijective: grid%8==0).
// Each XCD receives a CONTIGUOUS run of logical tiles -> operand panels shared by
// neighboring tiles stay in that XCD's L2 (scores FETCH 114->67.6 MB = mask-only).
// MODE 0: QKV epilogue (bias; cols>=2048 pre-transposed into vtOut)
// MODE 2: scores epilogue: P = exp(v*scale + mask) bf16; rowsum[row] += partials.
//         Mask read as 4 batches of 16 direct global loads — measured optimum:
//         beats hoist-64 (76.2), LDS-staged (73.5), scratch (141), pre-loop pin.
// MODE 4: PV epilogue: fp32, v / rowsum[row]
template <int MODE>
__global__ __launch_bounds__(256, 2) void gemm_bt(
    const u16* __restrict__ A, const u16* __restrict__ Bt, void* __restrict__ C,
    u16* __restrict__ vtOut, const float* __restrict__ bias,
    float* __restrict__ rsum, const float* __restrict__ maskG,
    int K, int lda, int ldb, int ldc,
    long sA_, long sB_, long sC_, float scale,
    int swq, int tpz, int nx)
{
  // XCD-chunked bijective swizzle, then decode (z, by, bx)
  const int b = blockIdx.x;
  const int s = (b & 7) * swq + (b >> 3);
  const int z = s / tpz, rem = s % tpz;
  const int bx = rem % nx, by = rem / nx;

  A += z * sA_;
  Bt += z * sB_;
  const long cbase = z * sC_;

  __shared__ __align__(16) u16 lA[BM * BK];   // 16 KB
  __shared__ __align__(16) u16 lB[BN * BK];   // 16 KB

  const int t = threadIdx.x;
  const int lane = t & 63;
  const int wave = t >> 6;
  const int wr = wave >> 1, wc = wave & 1;
  const int m0 = by * BM, n0 = bx * BN;

  // Staging: LDS [128 rows][8 chunks of 8 u16]; slot s of row r holds global
  // chunk s ^ (r&7) -> conflict-free ds_read_b128; linear LDS dest (rule 21).
  const int srow = t >> 3;
  const int schunk = (t & 7) ^ (srow & 7);
  const u16* aS = A + (long)(m0 + srow) * lda + schunk * 8;
  const u16* bS = Bt + (long)(n0 + srow) * ldb + schunk * 8;

  f32x4 acc[4][4] = {};
  const int fr = lane & 15;
  const int q4 = lane >> 4;

  for (int k0 = 0; k0 < K; k0 += BK) {
    __syncthreads();                 // prior LDS reads done before overwrite
#pragma unroll
    for (int i = 0; i < 4; i++) {
      load_lds16(aS + k0 + (long)(i * 32) * lda, &lA[(i * 256 + t) * 8]);
      load_lds16(bS + k0 + (long)(i * 32) * ldb, &lB[(i * 256 + t) * 8]);
    }
    __syncthreads();                 // drain global_load_lds
#pragma unroll
    for (int kk = 0; kk < 2; kk++) {
      const int ch = kk * 4 + q4;
      short8 aF[4], bF[4];
#pragma unroll
      for (int i = 0; i < 4; i++) {
        int row = wr * 64 + i * 16 + fr;
        aF[i] = *(const short8*)&lA[row * BK + ((ch ^ (row & 7)) * 8)];
      }
#pragma unroll
      for (int j = 0; j < 4; j++) {
        int row = wc * 64 + j * 16 + fr;
        bF[j] = *(const short8*)&lB[row * BK + ((ch ^ (row & 7)) * 8)];
      }
#pragma unroll
      for (int i = 0; i < 4; i++)
#pragma unroll
        for (int j = 0; j < 4; j++)
          acc[i][j] = __builtin_amdgcn_mfma_f32_16x16x32_bf16(aF[i], bF[j], acc[i][j], 0, 0, 0);
    }
  }

  // epilogue: C/D layout col = lane&15, row = (lane>>4)*4 + r
  const int r0 = q4 * 4;
  if (MODE == 2) {
    const float* mk = maskG + (long)z * 2048 * 2048;
    u16* Pout = (u16*)C + cbase;
    float* rz = rsum + (long)z * 2048;
#pragma unroll
    for (int i = 0; i < 4; i++) {
      const int row = m0 + wr * 64 + i * 16 + r0;
      float ml[4][4];
#pragma unroll
      for (int j = 0; j < 4; j++) {
        const int col = n0 + wc * 64 + j * 16 + fr;
#pragma unroll
        for (int r = 0; r < 4; r++)
          ml[j][r] = mk[(long)(row + r) * 2048 + col];   // 16 loads batched
      }
      float rs[4] = {0.f, 0.f, 0.f, 0.f};
#pragma unroll
      for (int j = 0; j < 4; j++) {
        const int col = n0 + wc * 64 + j * 16 + fr;
#pragma unroll
        for (int r = 0; r < 4; r++) {
          float e = __expf(acc[i][j][r] * scale + ml[j][r]);
          Pout[(long)(row + r) * ldc + col] = f2b(e);
          rs[r] += e;
        }
      }
#pragma unroll
      for (int r = 0; r < 4; r++) {
        float s2 = rs[r];
        s2 += __shfl_xor(s2, 1); s2 += __shfl_xor(s2, 2);
        s2 += __shfl_xor(s2, 4); s2 += __shfl_xor(s2, 8);
        if (fr == 0) atomicAdd(&rz[row + r], s2);
      }
    }
  } else if (MODE == 0) {
#pragma unroll
    for (int i = 0; i < 4; i++) {
#pragma unroll
      for (int j = 0; j < 4; j++) {
        const int row = m0 + wr * 64 + i * 16 + r0;
        const int col = n0 + wc * 64 + j * 16 + fr;
        const float b2 = bias[col];
        if (col >= 2048) {
          u16x4 o = { f2b(acc[i][j][0] + b2), f2b(acc[i][j][1] + b2),
                      f2b(acc[i][j][2] + b2), f2b(acc[i][j][3] + b2) };
          *(u16x4*)(vtOut + (long)(col - 2048) * 8192 + row) = o;
        } else {
#pragma unroll
          for (int r = 0; r < 4; r++)
            ((u16*)C)[(long)(row + r) * ldc + col] = f2b(acc[i][j][r] + b2);
        }
      }
    }
  } else {
    const float* lz = rsum + (long)z * 2048;
#pragma unroll
    for (int i = 0; i < 4; i++) {
      const int row = m0 + wr * 64 + i * 16 + r0;
      float inv[4];
#pragma unroll
      for (int r = 0; r < 4; r++) inv[r] = 1.0f / lz[row + r];
#pragma unroll
      for (int j = 0; j < 4; j++) {
        const int col = n0 + wc * 64 + j * 16 + fr;
#pragma unroll
        for (int r = 0; r < 4; r++)
          ((float*)C)[cbase + (long)(row + r) * ldc + col] = acc[i][j][r] * inv[r];
      }
    }
  }
}

// ---------------- launch ----------------
extern "C" void kernel_launch(void* const* d_in, const int* in_sizes, int n_in,
                              void* d_out, int out_size, void* d_ws, size_t ws_size,
                              hipStream_t stream) {
  const float* x    = (const float*)d_in[0];   // [4,2048,1024]
  const float* mask = (const float*)d_in[1];   // [4,2048,2048]
  const float* Wq   = (const float*)d_in[2];
  const float* bq   = (const float*)d_in[3];
  const float* Wk   = (const float*)d_in[4];
  const float* bk   = (const float*)d_in[5];
  const float* Wv   = (const float*)d_in[6];
  const float* bv   = (const float*)d_in[7];
  float* out = (float*)d_out;

  char* w = (char*)d_ws;
  u16*   xb    = (u16*)(w);                 // x bf16      [8192,1024]
  u16*   wT    = (u16*)(w + 16777216);      // [Wq;Wk;Wv]^T bf16 [3072,1024]
  float* biasC = (float*)(w + 23068672);    // concat bias [3072]
  u16*   QKV   = (u16*)(w + 23081088);      // Q,K bf16    [8192,3072]
  u16*   Vt    = (u16*)(w + 73414016);      // V^T bf16    [1024,8192]
  u16*   Pp    = (u16*)(w + 90191232);      // P bf16      [4,2048,2048]
  float* rowsum= (float*)(w + 123745664);   // row sums    [8192]

  prep<<<8192 + 3072 + 44, 256, 0, stream>>>(x, xb, Wq, Wk, Wv, wT, bq, bk, bv, biasC, rowsum);

  // QKV: [8192,1024] x [3072,1024]^T -> Q,K + V^T.  1536 tiles, 24 per row.
  gemm_bt<0><<<1536, 256, 0, stream>>>(xb, wT, QKV, Vt, biasC, nullptr, nullptr,
      1024, 1024, 1024, 3072, 0, 0, 0, 1.0f,
      192, 1536, 24);

  // scores: P = exp(QK^T/32 + mask), rowsum in-epilogue.  1024 tiles = 4z x 16 x 16.
  gemm_bt<2><<<1024, 256, 0, stream>>>(QKV, QKV + 1024, Pp, nullptr, nullptr, rowsum, mask,
      1024, 3072, 3072, 2048,
      2048L * 3072, 2048L * 3072, 2048L * 2048, 0.03125f,
      128, 256, 16);

  // PV: out = (P V) / rowsum.  512 tiles = 4z x 16 x 8.
  gemm_bt<4><<<512, 256, 0, stream>>>(Pp, Vt, out, nullptr, nullptr, rowsum, nullptr,
      2048, 2048, 8192, 1024,
      2048L * 2048, 2048L, 2048L * 1024, 1.0f,
      64, 128, 8);
}